// Round 6
// baseline (93.717 us; speedup 1.0000x reference)
//
#include <hip/hip_runtime.h>
#include <hip/hip_cooperative_groups.h>
#include <math.h>

namespace cg = cooperative_groups;

#define GRIDN 28
#define NPTS 784
#define BATCH 128
#define TT 25
#define KMAX 2
#define FOUT 50
#define NCLS 10
#define M0F 0.05f
#define NOFF 3025          // 55*55 relative offsets (dx,dy in [-27,27])
#define NOFFP 3032         // padded to multiple of 8 with invalid sentinels
#define D2MAX 1459         // d2 <= 2*27^2 = 1458

// ---------------------------------------------------------------------------
// Compile-time offset table: all (dx,dy) sorted ascending by d2 = dx^2+dy^2,
// ties broken by lex (dx,dy) == ascending neighbor index for any fixed point
// (bit-identical visit order to the verified round-2..5 kernels).
// Packed: (d2<<12) | ((dx+27)<<6) | (dy+27). Constexpr counting sort.
// Padding entries have dx+27=63 -> always out of bounds -> wj=0 (no-op).
// ---------------------------------------------------------------------------
struct OffTab { int v[NOFFP]; };

constexpr OffTab make_offtab() {
    OffTab t{};
    int cnt[D2MAX] = {};
    for (int e = 0; e < NOFF; ++e) {
        int dx = e / 55 - 27, dy = e % 55 - 27;
        cnt[dx * dx + dy * dy]++;
    }
    int base[D2MAX] = {};
    int s = 0;
    for (int d = 0; d < D2MAX; ++d) { base[d] = s; s += cnt[d]; }
    for (int e = 0; e < NOFF; ++e) {          // ascending e => stable ties
        int dxp = e / 55, dyp = e % 55;
        int dx = dxp - 27, dy = dyp - 27;
        int d2 = dx * dx + dy * dy;
        t.v[base[d2]++] = (d2 << 12) | (dxp << 6) | dyp;
    }
    for (int e = NOFF; e < NOFFP; ++e) t.v[e] = (63 << 6) | 63;
    return t;
}
__constant__ OffTab c_off = make_offtab();

// Inter-block scratch (fully rewritten every call; deterministic).
__device__ float g_x1[BATCH * FOUT];

// ---------------------------------------------------------------------------
// Single cooperative kernel: 128 blocks x 1024 threads, one grid.sync().
// Phase 1 (block = batch b): stage w -> bound -> chunked early-exit dtm scan
//   (LDS only) -> 5-pt neighborhood max -> 25 tents/top-2 -> topo-GEMM
//   -> g_x1[b][:].
// grid.sync()
// Phase 2 (block 0 only): batchnorm stats + signal + relu + final GEMM.
// d_out = [out (128x10), signal (50)].
// ---------------------------------------------------------------------------
__global__ __launch_bounds__(1024) void k_all(
        const float* __restrict__ w,
        const float* __restrict__ W_topo, const float* __restrict__ b_topo,
        const float* __restrict__ gamma,  const float* __restrict__ beta,
        const float* __restrict__ W_fc,   const float* __restrict__ b_fc,
        float* __restrict__ out) {
    __shared__ float wl[NPTS];
    __shared__ float fl[NPTS];
    __shared__ float dl[NPTS];
    __shared__ float sland[TT * KMAX];
    __shared__ float red[16];
    __shared__ float sbound;
    __shared__ float x1l[BATCH * FOUT];      // phase-2 (block 0) staging
    __shared__ float wfc[FOUT * NCLS];

    cg::grid_group grid = cg::this_grid();
    const int b = blockIdx.x;
    const int tid = threadIdx.x;

    // ---- Phase 1A: stage w, block-reduce sum -> bound ----
    float v = 0.f;
    if (tid < NPTS) { v = w[b * NPTS + tid]; wl[tid] = v; }
    float s = v;
    for (int off = 32; off > 0; off >>= 1) s += __shfl_xor(s, off);
    if ((tid & 63) == 0) red[tid >> 6] = s;
    __syncthreads();
    if (tid < 64) {
        float r2 = (tid < 16) ? red[tid] : 0.f;
        for (int off = 8; off > 0; off >>= 1) r2 += __shfl_xor(r2, off);
        if (tid == 0) sbound = M0F * r2;
    }
    __syncthreads();
    const float bound = sbound;

    // ---- Phase 1B: chunked early-exit dtm scan (all reads from LDS) ----
    if (tid < NPTS) {
        const int ix = tid / GRIDN, iy = tid % GRIDN;
        float cum = 0.f, acc = 0.f;
        for (int r = 0; r < NOFFP; r += 8) {
            int pk[8];
            #pragma unroll
            for (int u = 0; u < 8; ++u) pk[u] = c_off.v[r + u]; // scalar loads
            float wj[8];
            #pragma unroll
            for (int u = 0; u < 8; ++u) {                       // 8 indep LDS reads
                int jx = ix + ((pk[u] >> 6) & 63) - 27;
                int jy = iy + (pk[u] & 63) - 27;
                bool valid = ((unsigned)jx < (unsigned)GRIDN) &
                             ((unsigned)jy < (unsigned)GRIDN);
                int j = valid ? (jx * GRIDN + jy) : 0;
                wj[u] = valid ? wl[j] : 0.f;
            }
            #pragma unroll
            for (int u = 0; u < 8; ++u) {                       // register-only
                float t = fminf(fmaxf(bound - cum, 0.f), wj[u]);
                acc += t * (float)(pk[u] >> 12);
                cum += wj[u];
            }
            if (cum >= bound) break;     // all later terms exactly 0
        }
        fl[tid] = sqrtf(fmaxf(acc / bound, 0.f));
    }
    __syncthreads();

    // ---- Phase 1C: 5-point neighborhood max ----
    if (tid < NPTS) {
        int r = tid / GRIDN, c = tid % GRIDN;
        float up = fl[(r > 0 ? r - 1 : 0) * GRIDN + c];
        float dn = fl[(r < GRIDN - 1 ? r + 1 : GRIDN - 1) * GRIDN + c];
        float lf = fl[r * GRIDN + (c > 0 ? c - 1 : 0)];
        float rt = fl[r * GRIDN + (c < GRIDN - 1 ? c + 1 : GRIDN - 1)];
        dl[tid] = fmaxf(fmaxf(fmaxf(up, dn), fmaxf(lf, rt)), fl[tid]);
    }
    __syncthreads();

    // ---- Phase 1D: 25 tents, per-wave top-2 ----
    const int wave = tid >> 6, lane = tid & 63;
    for (int t = wave; t < TT; t += 16) {
        float tv = (t == TT - 1) ? 2.0f : (float)t * (2.0f / (float)(TT - 1));
        float m1 = 0.f, m2 = 0.f;
        for (int p = lane; p < NPTS; p += 64) {
            float tent = fmaxf(fminf(tv - fl[p], dl[p] - tv), 0.f);
            if (tent > m1) { m2 = m1; m1 = tent; }
            else m2 = fmaxf(m2, tent);
        }
        for (int off = 32; off > 0; off >>= 1) {
            float o1 = __shfl_xor(m1, off), o2 = __shfl_xor(m2, off);
            float nm2 = fmaxf(fminf(m1, o1), fmaxf(m2, o2));
            m1 = fmaxf(m1, o1); m2 = nm2;
        }
        if (lane == 0) {
            sland[2 * t]     = m1;
            sland[2 * t + 1] = m2;
        }
    }
    __syncthreads();

    // ---- Phase 1E: x1[b][:] = sland @ W_topo + b_topo ----
    if (tid < FOUT) {
        float acc = b_topo[tid];
        #pragma unroll
        for (int k = 0; k < TT * KMAX; ++k)
            acc += sland[k] * W_topo[k * FOUT + tid];
        g_x1[b * FOUT + tid] = acc;
    }
    __threadfence();

    grid.sync();

    // ---- Phase 2 (block 0): batchnorm + signal + head GEMM ----
    if (b != 0) return;

    for (int e = tid; e < BATCH * FOUT; e += 1024) x1l[e] = g_x1[e];
    if (tid < FOUT * NCLS) wfc[tid] = W_fc[tid];
    __syncthreads();

    if (tid < FOUT * 16) {
        const int f = tid >> 4, sub = tid & 15;
        float vals[8];
        float su = 0.f, sa = 0.f;
        #pragma unroll
        for (int k = 0; k < 8; ++k) {
            float vv = x1l[(sub + 16 * k) * FOUT + f];
            vals[k] = vv;
            su += vv;
            sa += fabsf(vv);
        }
        #pragma unroll
        for (int off = 8; off > 0; off >>= 1) {
            su += __shfl_xor(su, off);
            sa += __shfl_xor(sa, off);
        }
        const float mu = su * (1.0f / (float)BATCH);
        if (sub == 0) out[BATCH * NCLS + f] = sa;          // signal
        float dv = 0.f;
        #pragma unroll
        for (int k = 0; k < 8; ++k) {
            float d = vals[k] - mu;
            dv += d * d;
        }
        #pragma unroll
        for (int off = 8; off > 0; off >>= 1) dv += __shfl_xor(dv, off);
        const float var = dv * (1.0f / (float)BATCH);
        const float rstd = 1.0f / sqrtf(var + 1e-5f);
        const float g = gamma[f], be = beta[f];
        #pragma unroll
        for (int k = 0; k < 8; ++k) {
            float y = g * (vals[k] - mu) * rstd + be;
            x1l[(sub + 16 * k) * FOUT + f] = fmaxf(y, 0.f);
        }
    }
    __syncthreads();

    for (int idx = tid; idx < BATCH * NCLS; idx += 1024) {
        const int bb = idx / NCLS, cc = idx % NCLS;
        float sacc = b_fc[cc];
        #pragma unroll
        for (int f = 0; f < FOUT; ++f)
            sacc += x1l[bb * FOUT + f] * wfc[f * NCLS + cc];
        out[idx] = sacc;
    }
}

extern "C" void kernel_launch(void* const* d_in, const int* in_sizes, int n_in,
                              void* d_out, int out_size, void* d_ws, size_t ws_size,
                              hipStream_t stream) {
    const float* input  = (const float*)d_in[0];
    const float* W_topo = (const float*)d_in[1];
    const float* b_topo = (const float*)d_in[2];
    const float* gamma  = (const float*)d_in[3];
    const float* beta   = (const float*)d_in[4];
    const float* W_fc   = (const float*)d_in[5];
    const float* b_fc   = (const float*)d_in[6];
    float* out = (float*)d_out;

    void* args[] = {(void*)&input, (void*)&W_topo, (void*)&b_topo,
                    (void*)&gamma, (void*)&beta, (void*)&W_fc, (void*)&b_fc,
                    (void*)&out};
    hipLaunchCooperativeKernel((const void*)k_all, dim3(BATCH), dim3(1024),
                               args, 0, stream);
}

// Round 7
// 59.339 us; speedup vs baseline: 1.5794x; 1.5794x over previous
//
#include <hip/hip_runtime.h>
#include <math.h>

#define GRIDN 28
#define NPTS 784
#define BATCH 128
#define TT 25
#define KMAX 2
#define FOUT 50
#define NCLS 10
#define M0F 0.05f
#define NOFF 3025          // 55*55 relative offsets (dx,dy in [-27,27])
#define NOFFP 3032         // padded to multiple of 8 with invalid sentinels
#define D2MAX 1459         // d2 <= 2*27^2 = 1458

// ---------------------------------------------------------------------------
// Compile-time offset table: all (dx,dy) sorted ascending by d2 = dx^2+dy^2,
// ties broken by lex (dx,dy) == ascending neighbor index for any fixed point
// (bit-identical visit order to the verified round-2..5 kernels).
// Packed: (d2<<12) | ((dx+27)<<6) | (dy+27). Constexpr counting sort.
// Padding entries have dx+27=63 -> always out of bounds -> wj=0 (no-op).
// ---------------------------------------------------------------------------
struct OffTab { int v[NOFFP]; };

constexpr OffTab make_offtab() {
    OffTab t{};
    int cnt[D2MAX] = {};
    for (int e = 0; e < NOFF; ++e) {
        int dx = e / 55 - 27, dy = e % 55 - 27;
        cnt[dx * dx + dy * dy]++;
    }
    int base[D2MAX] = {};
    int s = 0;
    for (int d = 0; d < D2MAX; ++d) { base[d] = s; s += cnt[d]; }
    for (int e = 0; e < NOFF; ++e) {          // ascending e => stable ties
        int dxp = e / 55, dyp = e % 55;
        int dx = dxp - 27, dy = dyp - 27;
        int d2 = dx * dx + dy * dy;
        t.v[base[d2]++] = (d2 << 12) | (dxp << 6) | dyp;
    }
    for (int e = NOFF; e < NOFFP; ++e) t.v[e] = (63 << 6) | 63;
    return t;
}
__constant__ OffTab c_off = make_offtab();

// Inter-block scratch + arrival counter (module scope; counter is returned to
// 0 at the end of EVERY launch -> replay-deterministic, immune to d_ws poison).
__device__ float        g_x1[BATCH * FOUT];
__device__ unsigned int g_cnt = 0;

// ---------------------------------------------------------------------------
// Single kernel, 128 blocks x 1024 threads. Block b = batch row b.
// Phase 1: stage w -> bound -> chunked early-exit dtm scan (LDS only)
//          -> 5-pt neighborhood max -> 25 tents/top-2 -> topo-GEMM -> g_x1.
// Arrival: __threadfence + atomicAdd; last block (old==127) alone runs
// Phase 2: batchnorm stats + signal + relu + final GEMM, then resets g_cnt.
// d_out = [out (128x10), signal (50)].
// ---------------------------------------------------------------------------
__global__ __launch_bounds__(1024) void k_all(
        const float* __restrict__ w,
        const float* __restrict__ W_topo, const float* __restrict__ b_topo,
        const float* __restrict__ gamma,  const float* __restrict__ beta,
        const float* __restrict__ W_fc,   const float* __restrict__ b_fc,
        float* __restrict__ out) {
    __shared__ float wl[NPTS];
    __shared__ float fl[NPTS];
    __shared__ float dl[NPTS];
    __shared__ float sland[TT * KMAX];
    __shared__ float red[16];
    __shared__ float sbound;
    __shared__ int   s_old;
    __shared__ float x1l[BATCH * FOUT];      // phase-2 (last block) staging
    __shared__ float wfc[FOUT * NCLS];

    const int b = blockIdx.x;
    const int tid = threadIdx.x;

    // ---- Phase 1A: stage w, block-reduce sum -> bound ----
    float v = 0.f;
    if (tid < NPTS) { v = w[b * NPTS + tid]; wl[tid] = v; }
    float s = v;
    for (int off = 32; off > 0; off >>= 1) s += __shfl_xor(s, off);
    if ((tid & 63) == 0) red[tid >> 6] = s;
    __syncthreads();
    if (tid < 64) {
        float r2 = (tid < 16) ? red[tid] : 0.f;
        for (int off = 8; off > 0; off >>= 1) r2 += __shfl_xor(r2, off);
        if (tid == 0) sbound = M0F * r2;
    }
    __syncthreads();
    const float bound = sbound;

    // ---- Phase 1B: chunked early-exit dtm scan (all reads from LDS) ----
    if (tid < NPTS) {
        const int ix = tid / GRIDN, iy = tid % GRIDN;
        float cum = 0.f, acc = 0.f;
        for (int r = 0; r < NOFFP; r += 8) {
            int pk[8];
            #pragma unroll
            for (int u = 0; u < 8; ++u) pk[u] = c_off.v[r + u]; // scalar loads
            float wj[8];
            #pragma unroll
            for (int u = 0; u < 8; ++u) {                       // 8 indep LDS reads
                int jx = ix + ((pk[u] >> 6) & 63) - 27;
                int jy = iy + (pk[u] & 63) - 27;
                bool valid = ((unsigned)jx < (unsigned)GRIDN) &
                             ((unsigned)jy < (unsigned)GRIDN);
                int j = valid ? (jx * GRIDN + jy) : 0;
                wj[u] = valid ? wl[j] : 0.f;
            }
            #pragma unroll
            for (int u = 0; u < 8; ++u) {                       // register-only
                float t = fminf(fmaxf(bound - cum, 0.f), wj[u]);
                acc += t * (float)(pk[u] >> 12);
                cum += wj[u];
            }
            if (cum >= bound) break;     // all later terms exactly 0
        }
        fl[tid] = sqrtf(fmaxf(acc / bound, 0.f));
    }
    __syncthreads();

    // ---- Phase 1C: 5-point neighborhood max ----
    if (tid < NPTS) {
        int r = tid / GRIDN, c = tid % GRIDN;
        float up = fl[(r > 0 ? r - 1 : 0) * GRIDN + c];
        float dn = fl[(r < GRIDN - 1 ? r + 1 : GRIDN - 1) * GRIDN + c];
        float lf = fl[r * GRIDN + (c > 0 ? c - 1 : 0)];
        float rt = fl[r * GRIDN + (c < GRIDN - 1 ? c + 1 : GRIDN - 1)];
        dl[tid] = fmaxf(fmaxf(fmaxf(up, dn), fmaxf(lf, rt)), fl[tid]);
    }
    __syncthreads();

    // ---- Phase 1D: 25 tents, per-wave top-2 ----
    const int wave = tid >> 6, lane = tid & 63;
    for (int t = wave; t < TT; t += 16) {
        float tv = (t == TT - 1) ? 2.0f : (float)t * (2.0f / (float)(TT - 1));
        float m1 = 0.f, m2 = 0.f;
        for (int p = lane; p < NPTS; p += 64) {
            float tent = fmaxf(fminf(tv - fl[p], dl[p] - tv), 0.f);
            if (tent > m1) { m2 = m1; m1 = tent; }
            else m2 = fmaxf(m2, tent);
        }
        for (int off = 32; off > 0; off >>= 1) {
            float o1 = __shfl_xor(m1, off), o2 = __shfl_xor(m2, off);
            float nm2 = fmaxf(fminf(m1, o1), fmaxf(m2, o2));
            m1 = fmaxf(m1, o1); m2 = nm2;
        }
        if (lane == 0) {
            sland[2 * t]     = m1;
            sland[2 * t + 1] = m2;
        }
    }
    __syncthreads();

    // ---- Phase 1E: x1[b][:] = sland @ W_topo + b_topo ----
    if (tid < FOUT) {
        float acc = b_topo[tid];
        #pragma unroll
        for (int k = 0; k < TT * KMAX; ++k)
            acc += sland[k] * W_topo[k * FOUT + tid];
        g_x1[b * FOUT + tid] = acc;
    }

    // ---- Arrival: release fence + device-scope atomic ----
    __threadfence();
    if (tid == 0) s_old = (int)atomicAdd(&g_cnt, 1u);
    __syncthreads();
    if (s_old != BATCH - 1) return;

    // ---- Phase 2 (last-arriving block only) ----
    __threadfence();   // acquire side

    for (int e = tid; e < BATCH * FOUT; e += 1024) x1l[e] = g_x1[e];
    if (tid < FOUT * NCLS) wfc[tid] = W_fc[tid];
    __syncthreads();

    if (tid < FOUT * 16) {
        const int f = tid >> 4, sub = tid & 15;
        float vals[8];
        float su = 0.f, sa = 0.f;
        #pragma unroll
        for (int k = 0; k < 8; ++k) {
            float vv = x1l[(sub + 16 * k) * FOUT + f];
            vals[k] = vv;
            su += vv;
            sa += fabsf(vv);
        }
        #pragma unroll
        for (int off = 8; off > 0; off >>= 1) {
            su += __shfl_xor(su, off);
            sa += __shfl_xor(sa, off);
        }
        const float mu = su * (1.0f / (float)BATCH);
        if (sub == 0) out[BATCH * NCLS + f] = sa;          // signal
        float dv = 0.f;
        #pragma unroll
        for (int k = 0; k < 8; ++k) {
            float d = vals[k] - mu;
            dv += d * d;
        }
        #pragma unroll
        for (int off = 8; off > 0; off >>= 1) dv += __shfl_xor(dv, off);
        const float var = dv * (1.0f / (float)BATCH);
        const float rstd = 1.0f / sqrtf(var + 1e-5f);
        const float g = gamma[f], be = beta[f];
        #pragma unroll
        for (int k = 0; k < 8; ++k) {
            float y = g * (vals[k] - mu) * rstd + be;
            x1l[(sub + 16 * k) * FOUT + f] = fmaxf(y, 0.f);
        }
    }
    __syncthreads();

    for (int idx = tid; idx < BATCH * NCLS; idx += 1024) {
        const int bb = idx / NCLS, cc = idx % NCLS;
        float sacc = b_fc[cc];
        #pragma unroll
        for (int f = 0; f < FOUT; ++f)
            sacc += x1l[bb * FOUT + f] * wfc[f * NCLS + cc];
        out[idx] = sacc;
    }

    __syncthreads();
    if (tid == 0) atomicExch(&g_cnt, 0u);   // leave counter clean for replay
}

extern "C" void kernel_launch(void* const* d_in, const int* in_sizes, int n_in,
                              void* d_out, int out_size, void* d_ws, size_t ws_size,
                              hipStream_t stream) {
    const float* input  = (const float*)d_in[0];
    const float* W_topo = (const float*)d_in[1];
    const float* b_topo = (const float*)d_in[2];
    const float* gamma  = (const float*)d_in[3];
    const float* beta   = (const float*)d_in[4];
    const float* W_fc   = (const float*)d_in[5];
    const float* b_fc   = (const float*)d_in[6];
    float* out = (float*)d_out;

    k_all<<<dim3(BATCH), dim3(1024), 0, stream>>>(input, W_topo, b_topo,
                                                  gamma, beta, W_fc, b_fc, out);
}

// Round 8
// 33.494 us; speedup vs baseline: 2.7980x; 1.7716x over previous
//
#include <hip/hip_runtime.h>
#include <math.h>

#define GRIDN 28
#define NPTS 784
#define BATCH 128
#define TT 25
#define KMAX 2
#define FOUT 50
#define NCLS 10
#define M0F 0.05f
#define NOFF 3025          // 55*55 relative offsets (dx,dy in [-27,27])
#define NOFFP 3032         // padded to multiple of 8 with invalid sentinels
#define D2MAX 1459         // d2 <= 2*27^2 = 1458

// ---------------------------------------------------------------------------
// Compile-time offset table: all (dx,dy) sorted ascending by d2 = dx^2+dy^2,
// ties broken by lex (dx,dy) == ascending neighbor index for any fixed point
// (bit-identical visit order to the verified round-2..5 kernels).
// Packed: (d2<<12) | ((dx+27)<<6) | (dy+27). Constexpr counting sort.
// Padding entries have dx+27=63 -> always out of bounds -> wj=0 (no-op).
// ---------------------------------------------------------------------------
struct OffTab { int v[NOFFP]; };

constexpr OffTab make_offtab() {
    OffTab t{};
    int cnt[D2MAX] = {};
    for (int e = 0; e < NOFF; ++e) {
        int dx = e / 55 - 27, dy = e % 55 - 27;
        cnt[dx * dx + dy * dy]++;
    }
    int base[D2MAX] = {};
    int s = 0;
    for (int d = 0; d < D2MAX; ++d) { base[d] = s; s += cnt[d]; }
    for (int e = 0; e < NOFF; ++e) {          // ascending e => stable ties
        int dxp = e / 55, dyp = e % 55;
        int dx = dxp - 27, dy = dyp - 27;
        int d2 = dx * dx + dy * dy;
        t.v[base[d2]++] = (d2 << 12) | (dxp << 6) | dyp;
    }
    for (int e = NOFF; e < NOFFP; ++e) t.v[e] = (63 << 6) | 63;
    return t;
}
__constant__ OffTab c_off = make_offtab();

// Inter-block scratch + arrival counter (module scope; counter is returned to
// 0 at the end of EVERY launch -> replay-deterministic, immune to d_ws poison).
__device__ float        g_x1[BATCH * FOUT];
__device__ unsigned int g_cnt = 0;

// ---------------------------------------------------------------------------
// Single kernel, 128 blocks x 1024 threads. Block b = batch row b.
// Phase 1: stage w -> bound -> chunked early-exit dtm scan (LDS only)
//          -> 5-pt neighborhood max -> 25 tents/top-2 -> topo-GEMM -> g_x1.
// Arrival: g_x1 row is stored by lanes 0..49 of wave 0; thread 0 (same wave,
//          so wave program order sequences stores -> fence -> atomic) issues
//          ONE device-scope release fence (single buffer_wbl2 per block, vs
//          2048 in R7) + atomicAdd. Last block (old==127) alone runs
// Phase 2: acquire fence, batchnorm stats + signal + relu + final GEMM,
//          then resets g_cnt.
// d_out = [out (128x10), signal (50)].
// ---------------------------------------------------------------------------
__global__ __launch_bounds__(1024) void k_all(
        const float* __restrict__ w,
        const float* __restrict__ W_topo, const float* __restrict__ b_topo,
        const float* __restrict__ gamma,  const float* __restrict__ beta,
        const float* __restrict__ W_fc,   const float* __restrict__ b_fc,
        float* __restrict__ out) {
    __shared__ float wl[NPTS];
    __shared__ float fl[NPTS];
    __shared__ float dl[NPTS];
    __shared__ float sland[TT * KMAX];
    __shared__ float red[16];
    __shared__ float sbound;
    __shared__ int   s_old;
    __shared__ float x1l[BATCH * FOUT];      // phase-2 (last block) staging
    __shared__ float wfc[FOUT * NCLS];

    const int b = blockIdx.x;
    const int tid = threadIdx.x;

    // ---- Phase 1A: stage w, block-reduce sum -> bound ----
    float v = 0.f;
    if (tid < NPTS) { v = w[b * NPTS + tid]; wl[tid] = v; }
    float s = v;
    for (int off = 32; off > 0; off >>= 1) s += __shfl_xor(s, off);
    if ((tid & 63) == 0) red[tid >> 6] = s;
    __syncthreads();
    if (tid < 64) {
        float r2 = (tid < 16) ? red[tid] : 0.f;
        for (int off = 8; off > 0; off >>= 1) r2 += __shfl_xor(r2, off);
        if (tid == 0) sbound = M0F * r2;
    }
    __syncthreads();
    const float bound = sbound;

    // ---- Phase 1B: chunked early-exit dtm scan (all reads from LDS) ----
    if (tid < NPTS) {
        const int ix = tid / GRIDN, iy = tid % GRIDN;
        float cum = 0.f, acc = 0.f;
        for (int r = 0; r < NOFFP; r += 8) {
            int pk[8];
            #pragma unroll
            for (int u = 0; u < 8; ++u) pk[u] = c_off.v[r + u]; // scalar loads
            float wj[8];
            #pragma unroll
            for (int u = 0; u < 8; ++u) {                       // 8 indep LDS reads
                int jx = ix + ((pk[u] >> 6) & 63) - 27;
                int jy = iy + (pk[u] & 63) - 27;
                bool valid = ((unsigned)jx < (unsigned)GRIDN) &
                             ((unsigned)jy < (unsigned)GRIDN);
                int j = valid ? (jx * GRIDN + jy) : 0;
                wj[u] = valid ? wl[j] : 0.f;
            }
            #pragma unroll
            for (int u = 0; u < 8; ++u) {                       // register-only
                float t = fminf(fmaxf(bound - cum, 0.f), wj[u]);
                acc += t * (float)(pk[u] >> 12);
                cum += wj[u];
            }
            if (cum >= bound) break;     // all later terms exactly 0
        }
        fl[tid] = sqrtf(fmaxf(acc / bound, 0.f));
    }
    __syncthreads();

    // ---- Phase 1C: 5-point neighborhood max ----
    if (tid < NPTS) {
        int r = tid / GRIDN, c = tid % GRIDN;
        float up = fl[(r > 0 ? r - 1 : 0) * GRIDN + c];
        float dn = fl[(r < GRIDN - 1 ? r + 1 : GRIDN - 1) * GRIDN + c];
        float lf = fl[r * GRIDN + (c > 0 ? c - 1 : 0)];
        float rt = fl[r * GRIDN + (c < GRIDN - 1 ? c + 1 : GRIDN - 1)];
        dl[tid] = fmaxf(fmaxf(fmaxf(up, dn), fmaxf(lf, rt)), fl[tid]);
    }
    __syncthreads();

    // ---- Phase 1D: 25 tents, per-wave top-2 ----
    const int wave = tid >> 6, lane = tid & 63;
    for (int t = wave; t < TT; t += 16) {
        float tv = (t == TT - 1) ? 2.0f : (float)t * (2.0f / (float)(TT - 1));
        float m1 = 0.f, m2 = 0.f;
        for (int p = lane; p < NPTS; p += 64) {
            float tent = fmaxf(fminf(tv - fl[p], dl[p] - tv), 0.f);
            if (tent > m1) { m2 = m1; m1 = tent; }
            else m2 = fmaxf(m2, tent);
        }
        for (int off = 32; off > 0; off >>= 1) {
            float o1 = __shfl_xor(m1, off), o2 = __shfl_xor(m2, off);
            float nm2 = fmaxf(fminf(m1, o1), fmaxf(m2, o2));
            m1 = fmaxf(m1, o1); m2 = nm2;
        }
        if (lane == 0) {
            sland[2 * t]     = m1;
            sland[2 * t + 1] = m2;
        }
    }
    __syncthreads();

    // ---- Phase 1E: x1[b][:] = sland @ W_topo + b_topo (lanes 0..49, wave 0)
    if (tid < FOUT) {
        float acc = b_topo[tid];
        #pragma unroll
        for (int k = 0; k < TT * KMAX; ++k)
            acc += sland[k] * W_topo[k * FOUT + tid];
        g_x1[b * FOUT + tid] = acc;
    }

    // ---- Arrival: ONE release fence + device-scope atomic (thread 0 only).
    // Stores above are by wave 0; thread 0 is in the same wave, so wave
    // program order sequences stores -> wbl2 -> atomic. One L2 writeback
    // per block instead of one per wave.
    if (tid == 0) {
        __threadfence();
        s_old = (int)atomicAdd(&g_cnt, 1u);
    }
    __syncthreads();
    if (s_old != BATCH - 1) return;

    // ---- Phase 2 (last-arriving block only) ----
    __threadfence();   // acquire: invalidate potentially-stale L2/L1 lines

    for (int e = tid; e < BATCH * FOUT; e += 1024) x1l[e] = g_x1[e];
    if (tid < FOUT * NCLS) wfc[tid] = W_fc[tid];
    __syncthreads();

    if (tid < FOUT * 16) {
        const int f = tid >> 4, sub = tid & 15;
        float vals[8];
        float su = 0.f, sa = 0.f;
        #pragma unroll
        for (int k = 0; k < 8; ++k) {
            float vv = x1l[(sub + 16 * k) * FOUT + f];
            vals[k] = vv;
            su += vv;
            sa += fabsf(vv);
        }
        #pragma unroll
        for (int off = 8; off > 0; off >>= 1) {
            su += __shfl_xor(su, off);
            sa += __shfl_xor(sa, off);
        }
        const float mu = su * (1.0f / (float)BATCH);
        if (sub == 0) out[BATCH * NCLS + f] = sa;          // signal
        float dv = 0.f;
        #pragma unroll
        for (int k = 0; k < 8; ++k) {
            float d = vals[k] - mu;
            dv += d * d;
        }
        #pragma unroll
        for (int off = 8; off > 0; off >>= 1) dv += __shfl_xor(dv, off);
        const float var = dv * (1.0f / (float)BATCH);
        const float rstd = 1.0f / sqrtf(var + 1e-5f);
        const float g = gamma[f], be = beta[f];
        #pragma unroll
        for (int k = 0; k < 8; ++k) {
            float y = g * (vals[k] - mu) * rstd + be;
            x1l[(sub + 16 * k) * FOUT + f] = fmaxf(y, 0.f);
        }
    }
    __syncthreads();

    for (int idx = tid; idx < BATCH * NCLS; idx += 1024) {
        const int bb = idx / NCLS, cc = idx % NCLS;
        float sacc = b_fc[cc];
        #pragma unroll
        for (int f = 0; f < FOUT; ++f)
            sacc += x1l[bb * FOUT + f] * wfc[f * NCLS + cc];
        out[idx] = sacc;
    }

    __syncthreads();
    if (tid == 0) atomicExch(&g_cnt, 0u);   // leave counter clean for replay
}

extern "C" void kernel_launch(void* const* d_in, const int* in_sizes, int n_in,
                              void* d_out, int out_size, void* d_ws, size_t ws_size,
                              hipStream_t stream) {
    const float* input  = (const float*)d_in[0];
    const float* W_topo = (const float*)d_in[1];
    const float* b_topo = (const float*)d_in[2];
    const float* gamma  = (const float*)d_in[3];
    const float* beta   = (const float*)d_in[4];
    const float* W_fc   = (const float*)d_in[5];
    const float* b_fc   = (const float*)d_in[6];
    float* out = (float*)d_out;

    k_all<<<dim3(BATCH), dim3(1024), 0, stream>>>(input, W_topo, b_topo,
                                                  gamma, beta, W_fc, b_fc, out);
}

// Round 9
// 33.001 us; speedup vs baseline: 2.8398x; 1.0149x over previous
//
#include <hip/hip_runtime.h>
#include <math.h>

#define GRIDN 28
#define NPTS 784
#define BATCH 128
#define TT 25
#define KMAX 2
#define FOUT 50
#define NCLS 10
#define M0F 0.05f
#define NOFF 3025          // 55*55 relative offsets (dx,dy in [-27,27])
#define NOFFP 3032         // padded to multiple of 8 with invalid sentinels
#define D2MAX 1459         // d2 <= 2*27^2 = 1458

// ---------------------------------------------------------------------------
// Compile-time offset table: all (dx,dy) sorted ascending by d2 = dx^2+dy^2,
// ties broken by lex (dx,dy) == ascending neighbor index for any fixed point
// (bit-identical visit order to the verified round-2..5 kernels).
// Packed: (d2<<12) | ((dx+27)<<6) | (dy+27). Constexpr counting sort.
// Padding entries have dx+27=63 -> always out of bounds -> wj=0 (no-op).
// ---------------------------------------------------------------------------
struct OffTab { int v[NOFFP]; };

constexpr OffTab make_offtab() {
    OffTab t{};
    int cnt[D2MAX] = {};
    for (int e = 0; e < NOFF; ++e) {
        int dx = e / 55 - 27, dy = e % 55 - 27;
        cnt[dx * dx + dy * dy]++;
    }
    int base[D2MAX] = {};
    int s = 0;
    for (int d = 0; d < D2MAX; ++d) { base[d] = s; s += cnt[d]; }
    for (int e = 0; e < NOFF; ++e) {          // ascending e => stable ties
        int dxp = e / 55, dyp = e % 55;
        int dx = dxp - 27, dy = dyp - 27;
        int d2 = dx * dx + dy * dy;
        t.v[base[d2]++] = (d2 << 12) | (dxp << 6) | dyp;
    }
    for (int e = NOFF; e < NOFFP; ++e) t.v[e] = (63 << 6) | 63;
    return t;
}
__constant__ OffTab c_off = make_offtab();

// Inter-block scratch + arrival counter (module scope; counter is returned to
// 0 at the end of EVERY launch -> replay-deterministic, immune to d_ws poison).
__device__ float        g_x1[BATCH * FOUT];
__device__ unsigned int g_cnt = 0;

// ---------------------------------------------------------------------------
// Single kernel, 128 blocks x 1024 threads. Block b = batch row b.
// Phase 1: stage w -> bound -> chunked early-exit dtm scan (LDS only)
//          -> 5-pt neighborhood max -> 25 tents/top-2 -> topo-GEMM -> g_x1.
// Arrival: g_x1 row is stored by lanes 0..49 of wave 0; thread 0 (same wave,
//          so wave program order sequences stores -> fence -> atomic) issues
//          ONE device-scope release fence (single buffer_wbl2 per block, vs
//          2048 in R7) + atomicAdd. Last block (old==127) alone runs
// Phase 2: acquire fence, batchnorm stats + signal + relu + final GEMM,
//          then resets g_cnt.
// d_out = [out (128x10), signal (50)].
// ---------------------------------------------------------------------------
__global__ __launch_bounds__(1024) void k_all(
        const float* __restrict__ w,
        const float* __restrict__ W_topo, const float* __restrict__ b_topo,
        const float* __restrict__ gamma,  const float* __restrict__ beta,
        const float* __restrict__ W_fc,   const float* __restrict__ b_fc,
        float* __restrict__ out) {
    __shared__ float wl[NPTS];
    __shared__ float fl[NPTS];
    __shared__ float dl[NPTS];
    __shared__ float sland[TT * KMAX];
    __shared__ float red[16];
    __shared__ float sbound;
    __shared__ int   s_old;
    __shared__ float x1l[BATCH * FOUT];      // phase-2 (last block) staging
    __shared__ float wfc[FOUT * NCLS];

    const int b = blockIdx.x;
    const int tid = threadIdx.x;

    // ---- Phase 1A: stage w, block-reduce sum -> bound ----
    float v = 0.f;
    if (tid < NPTS) { v = w[b * NPTS + tid]; wl[tid] = v; }
    float s = v;
    for (int off = 32; off > 0; off >>= 1) s += __shfl_xor(s, off);
    if ((tid & 63) == 0) red[tid >> 6] = s;
    __syncthreads();
    if (tid < 64) {
        float r2 = (tid < 16) ? red[tid] : 0.f;
        for (int off = 8; off > 0; off >>= 1) r2 += __shfl_xor(r2, off);
        if (tid == 0) sbound = M0F * r2;
    }
    __syncthreads();
    const float bound = sbound;

    // ---- Phase 1B: chunked early-exit dtm scan (all reads from LDS) ----
    if (tid < NPTS) {
        const int ix = tid / GRIDN, iy = tid % GRIDN;
        float cum = 0.f, acc = 0.f;
        for (int r = 0; r < NOFFP; r += 8) {
            int pk[8];
            #pragma unroll
            for (int u = 0; u < 8; ++u) pk[u] = c_off.v[r + u]; // scalar loads
            float wj[8];
            #pragma unroll
            for (int u = 0; u < 8; ++u) {                       // 8 indep LDS reads
                int jx = ix + ((pk[u] >> 6) & 63) - 27;
                int jy = iy + (pk[u] & 63) - 27;
                bool valid = ((unsigned)jx < (unsigned)GRIDN) &
                             ((unsigned)jy < (unsigned)GRIDN);
                int j = valid ? (jx * GRIDN + jy) : 0;
                wj[u] = valid ? wl[j] : 0.f;
            }
            #pragma unroll
            for (int u = 0; u < 8; ++u) {                       // register-only
                float t = fminf(fmaxf(bound - cum, 0.f), wj[u]);
                acc += t * (float)(pk[u] >> 12);
                cum += wj[u];
            }
            if (cum >= bound) break;     // all later terms exactly 0
        }
        fl[tid] = sqrtf(fmaxf(acc / bound, 0.f));
    }
    __syncthreads();

    // ---- Phase 1C: 5-point neighborhood max ----
    if (tid < NPTS) {
        int r = tid / GRIDN, c = tid % GRIDN;
        float up = fl[(r > 0 ? r - 1 : 0) * GRIDN + c];
        float dn = fl[(r < GRIDN - 1 ? r + 1 : GRIDN - 1) * GRIDN + c];
        float lf = fl[r * GRIDN + (c > 0 ? c - 1 : 0)];
        float rt = fl[r * GRIDN + (c < GRIDN - 1 ? c + 1 : GRIDN - 1)];
        dl[tid] = fmaxf(fmaxf(fmaxf(up, dn), fmaxf(lf, rt)), fl[tid]);
    }
    __syncthreads();

    // ---- Phase 1D: 25 tents, per-wave top-2 ----
    const int wave = tid >> 6, lane = tid & 63;
    for (int t = wave; t < TT; t += 16) {
        float tv = (t == TT - 1) ? 2.0f : (float)t * (2.0f / (float)(TT - 1));
        float m1 = 0.f, m2 = 0.f;
        for (int p = lane; p < NPTS; p += 64) {
            float tent = fmaxf(fminf(tv - fl[p], dl[p] - tv), 0.f);
            if (tent > m1) { m2 = m1; m1 = tent; }
            else m2 = fmaxf(m2, tent);
        }
        for (int off = 32; off > 0; off >>= 1) {
            float o1 = __shfl_xor(m1, off), o2 = __shfl_xor(m2, off);
            float nm2 = fmaxf(fminf(m1, o1), fmaxf(m2, o2));
            m1 = fmaxf(m1, o1); m2 = nm2;
        }
        if (lane == 0) {
            sland[2 * t]     = m1;
            sland[2 * t + 1] = m2;
        }
    }
    __syncthreads();

    // ---- Phase 1E: x1[b][:] = sland @ W_topo + b_topo (lanes 0..49, wave 0)
    if (tid < FOUT) {
        float acc = b_topo[tid];
        #pragma unroll
        for (int k = 0; k < TT * KMAX; ++k)
            acc += sland[k] * W_topo[k * FOUT + tid];
        g_x1[b * FOUT + tid] = acc;
    }

    // ---- Arrival: ONE release fence + device-scope atomic (thread 0 only).
    // Stores above are by wave 0; thread 0 is in the same wave, so wave
    // program order sequences stores -> wbl2 -> atomic. One L2 writeback
    // per block instead of one per wave.
    if (tid == 0) {
        __threadfence();
        s_old = (int)atomicAdd(&g_cnt, 1u);
    }
    __syncthreads();
    if (s_old != BATCH - 1) return;

    // ---- Phase 2 (last-arriving block only) ----
    __threadfence();   // acquire: invalidate potentially-stale L2/L1 lines

    for (int e = tid; e < BATCH * FOUT; e += 1024) x1l[e] = g_x1[e];
    if (tid < FOUT * NCLS) wfc[tid] = W_fc[tid];
    __syncthreads();

    if (tid < FOUT * 16) {
        const int f = tid >> 4, sub = tid & 15;
        float vals[8];
        float su = 0.f, sa = 0.f;
        #pragma unroll
        for (int k = 0; k < 8; ++k) {
            float vv = x1l[(sub + 16 * k) * FOUT + f];
            vals[k] = vv;
            su += vv;
            sa += fabsf(vv);
        }
        #pragma unroll
        for (int off = 8; off > 0; off >>= 1) {
            su += __shfl_xor(su, off);
            sa += __shfl_xor(sa, off);
        }
        const float mu = su * (1.0f / (float)BATCH);
        if (sub == 0) out[BATCH * NCLS + f] = sa;          // signal
        float dv = 0.f;
        #pragma unroll
        for (int k = 0; k < 8; ++k) {
            float d = vals[k] - mu;
            dv += d * d;
        }
        #pragma unroll
        for (int off = 8; off > 0; off >>= 1) dv += __shfl_xor(dv, off);
        const float var = dv * (1.0f / (float)BATCH);
        const float rstd = 1.0f / sqrtf(var + 1e-5f);
        const float g = gamma[f], be = beta[f];
        #pragma unroll
        for (int k = 0; k < 8; ++k) {
            float y = g * (vals[k] - mu) * rstd + be;
            x1l[(sub + 16 * k) * FOUT + f] = fmaxf(y, 0.f);
        }
    }
    __syncthreads();

    for (int idx = tid; idx < BATCH * NCLS; idx += 1024) {
        const int bb = idx / NCLS, cc = idx % NCLS;
        float sacc = b_fc[cc];
        #pragma unroll
        for (int f = 0; f < FOUT; ++f)
            sacc += x1l[bb * FOUT + f] * wfc[f * NCLS + cc];
        out[idx] = sacc;
    }

    __syncthreads();
    if (tid == 0) atomicExch(&g_cnt, 0u);   // leave counter clean for replay
}

extern "C" void kernel_launch(void* const* d_in, const int* in_sizes, int n_in,
                              void* d_out, int out_size, void* d_ws, size_t ws_size,
                              hipStream_t stream) {
    const float* input  = (const float*)d_in[0];
    const float* W_topo = (const float*)d_in[1];
    const float* b_topo = (const float*)d_in[2];
    const float* gamma  = (const float*)d_in[3];
    const float* beta   = (const float*)d_in[4];
    const float* W_fc   = (const float*)d_in[5];
    const float* b_fc   = (const float*)d_in[6];
    float* out = (float*)d_out;

    k_all<<<dim3(BATCH), dim3(1024), 0, stream>>>(input, W_topo, b_topo,
                                                  gamma, beta, W_fc, b_fc, out);
}

// Round 10
// 29.854 us; speedup vs baseline: 3.1392x; 1.1054x over previous
//
#include <hip/hip_runtime.h>
#include <math.h>

#define GRIDN 28
#define NPTS 784
#define BATCH 128
#define TT 25
#define KMAX 2
#define FOUT 50
#define NCLS 10
#define M0F 0.05f
#define NOFF 3025          // 55*55 relative offsets (dx,dy in [-27,27])
#define NOFFP 3032         // padded to multiple of 8 with invalid sentinels
#define D2MAX 1459         // d2 <= 2*27^2 = 1458
#define NSUB 8             // dtm sub-blocks per batch
#define PPS (NPTS / NSUB)  // 98 points per sub-block

// ---------------------------------------------------------------------------
// Compile-time offset table: all (dx,dy) sorted ascending by d2 = dx^2+dy^2,
// ties broken by lex (dx,dy) == ascending neighbor index for any fixed point
// (bit-identical visit order to the verified round-2..9 kernels).
// Packed: (d2<<12) | ((dx+27)<<6) | (dy+27). Constexpr counting sort.
// Padding entries have dx+27=63 -> always out of bounds -> wj=0 (no-op).
// ---------------------------------------------------------------------------
struct OffTab { int v[NOFFP]; };

constexpr OffTab make_offtab() {
    OffTab t{};
    int cnt[D2MAX] = {};
    for (int e = 0; e < NOFF; ++e) {
        int dx = e / 55 - 27, dy = e % 55 - 27;
        cnt[dx * dx + dy * dy]++;
    }
    int base[D2MAX] = {};
    int s = 0;
    for (int d = 0; d < D2MAX; ++d) { base[d] = s; s += cnt[d]; }
    for (int e = 0; e < NOFF; ++e) {          // ascending e => stable ties
        int dxp = e / 55, dyp = e % 55;
        int dx = dxp - 27, dy = dyp - 27;
        int d2 = dx * dx + dy * dy;
        t.v[base[d2]++] = (d2 << 12) | (dxp << 6) | dyp;
    }
    for (int e = NOFF; e < NOFFP; ++e) t.v[e] = (63 << 6) | 63;
    return t;
}
__constant__ OffTab c_off = make_offtab();

// Inter-kernel / inter-block scratch. g_cnt is module scope (immune to d_ws
// poison) and returned to 0 at the end of every launch -> replay-safe.
__device__ float        g_f[BATCH * NPTS];
__device__ float        g_x1[BATCH * FOUT];
__device__ unsigned int g_cnt = 0;

// ---------------------------------------------------------------------------
// Kernel 1: DTM scan, 8 sub-blocks per batch (1024 blocks x 128 thr -> full
// GPU, ~4 blocks/CU). Verified R5 body. K1->K2 visibility is guaranteed by
// the dispatch boundary (graph edge) -- no fences needed.
// ---------------------------------------------------------------------------
__global__ __launch_bounds__(128) void k_dtm(const float* __restrict__ w) {
    __shared__ float wl[NPTS];
    __shared__ float red[2];
    const int b   = blockIdx.x >> 3;
    const int sub = blockIdx.x & 7;
    const int tid = threadIdx.x;

    float s = 0.f;
    for (int p = tid; p < NPTS; p += 128) {
        float v = w[b * NPTS + p];
        wl[p] = v;
        s += v;
    }
    for (int off = 32; off > 0; off >>= 1) s += __shfl_xor(s, off);
    if ((tid & 63) == 0) red[tid >> 6] = s;
    __syncthreads();
    const float bound = M0F * (red[0] + red[1]);

    if (tid < PPS) {
        const int p = sub * PPS + tid;
        const int ix = p / GRIDN, iy = p % GRIDN;
        float cum = 0.f, acc = 0.f;
        for (int r = 0; r < NOFFP; r += 8) {
            int pk[8];
            #pragma unroll
            for (int u = 0; u < 8; ++u) pk[u] = c_off.v[r + u]; // scalar loads
            float wj[8];
            #pragma unroll
            for (int u = 0; u < 8; ++u) {                       // 8 indep LDS reads
                int jx = ix + ((pk[u] >> 6) & 63) - 27;
                int jy = iy + (pk[u] & 63) - 27;
                bool valid = ((unsigned)jx < (unsigned)GRIDN) &
                             ((unsigned)jy < (unsigned)GRIDN);
                int j = valid ? (jx * GRIDN + jy) : 0;
                wj[u] = valid ? wl[j] : 0.f;
            }
            #pragma unroll
            for (int u = 0; u < 8; ++u) {                       // register-only
                float t = fminf(fmaxf(bound - cum, 0.f), wj[u]);
                acc += t * (float)(pk[u] >> 12);
                cum += wj[u];
            }
            if (cum >= bound) break;     // all later terms exactly 0
        }
        g_f[b * NPTS + p] = sqrtf(fmaxf(acc / bound, 0.f));
    }
}

// ---------------------------------------------------------------------------
// Kernel 2: landscape + topo-GEMM per batch block; last-arriving block runs
// batchnorm + signal + head. Arrival path has ZERO cache-maintenance ops:
//  - x1 row stored with agent-scope RELAXED atomic stores (coherent point,
//    no buffer_wbl2),
//  - thread 0 (same wave as the 50 storing lanes) waits vmcnt(0) -- wave
//    program order covers the whole row -- then relaxed agent fetch_add,
//  - last block reads g_x1 with agent-scope RELAXED atomic loads (coherent,
//    no buffer_inv).
// d_out = [out (128x10), signal (50)].
// ---------------------------------------------------------------------------
__global__ __launch_bounds__(1024) void k_landbn(
        const float* __restrict__ W_topo, const float* __restrict__ b_topo,
        const float* __restrict__ gamma,  const float* __restrict__ beta,
        const float* __restrict__ W_fc,   const float* __restrict__ b_fc,
        float* __restrict__ out) {
    __shared__ float fl[NPTS];
    __shared__ float dl[NPTS];
    __shared__ float sland[TT * KMAX];
    __shared__ int   s_old;
    __shared__ float x1l[BATCH * FOUT];      // last-block staging
    __shared__ float wfc[FOUT * NCLS];

    const int b = blockIdx.x;
    const int tid = threadIdx.x;

    // ---- landscape input (plain loads; K1->K2 dispatch edge = visibility)
    if (tid < NPTS) fl[tid] = g_f[b * NPTS + tid];
    __syncthreads();

    // ---- 5-point neighborhood max ----
    if (tid < NPTS) {
        int r = tid / GRIDN, c = tid % GRIDN;
        float up = fl[(r > 0 ? r - 1 : 0) * GRIDN + c];
        float dn = fl[(r < GRIDN - 1 ? r + 1 : GRIDN - 1) * GRIDN + c];
        float lf = fl[r * GRIDN + (c > 0 ? c - 1 : 0)];
        float rt = fl[r * GRIDN + (c < GRIDN - 1 ? c + 1 : GRIDN - 1)];
        dl[tid] = fmaxf(fmaxf(fmaxf(up, dn), fmaxf(lf, rt)), fl[tid]);
    }
    __syncthreads();

    // ---- 25 tents, per-wave top-2 ----
    const int wave = tid >> 6, lane = tid & 63;
    for (int t = wave; t < TT; t += 16) {
        float tv = (t == TT - 1) ? 2.0f : (float)t * (2.0f / (float)(TT - 1));
        float m1 = 0.f, m2 = 0.f;
        for (int p = lane; p < NPTS; p += 64) {
            float tent = fmaxf(fminf(tv - fl[p], dl[p] - tv), 0.f);
            if (tent > m1) { m2 = m1; m1 = tent; }
            else m2 = fmaxf(m2, tent);
        }
        for (int off = 32; off > 0; off >>= 1) {
            float o1 = __shfl_xor(m1, off), o2 = __shfl_xor(m2, off);
            float nm2 = fmaxf(fminf(m1, o1), fmaxf(m2, o2));
            m1 = fmaxf(m1, o1); m2 = nm2;
        }
        if (lane == 0) {
            sland[2 * t]     = m1;
            sland[2 * t + 1] = m2;
        }
    }
    __syncthreads();

    // ---- topo-GEMM: x1[b][:] (lanes 0..49 of wave 0), agent-scope stores
    if (tid < FOUT) {
        float acc = b_topo[tid];
        #pragma unroll
        for (int k = 0; k < TT * KMAX; ++k)
            acc += sland[k] * W_topo[k * FOUT + tid];
        __hip_atomic_store(&g_x1[b * FOUT + tid], acc,
                           __ATOMIC_RELAXED, __HIP_MEMORY_SCOPE_AGENT);
    }

    // ---- arrival: wave-level waitcnt (covers lanes 0..49's stores) + atomic
    if (tid == 0) {
        asm volatile("s_waitcnt vmcnt(0)" ::: "memory");
        s_old = (int)__hip_atomic_fetch_add(&g_cnt, 1u, __ATOMIC_RELAXED,
                                            __HIP_MEMORY_SCOPE_AGENT);
    }
    __syncthreads();
    if (s_old != BATCH - 1) return;

    // ---- Phase 2 (last-arriving block only): coherent loads of x1 ----
    for (int e = tid; e < BATCH * FOUT; e += 1024)
        x1l[e] = __hip_atomic_load(&g_x1[e], __ATOMIC_RELAXED,
                                   __HIP_MEMORY_SCOPE_AGENT);
    if (tid < FOUT * NCLS) wfc[tid] = W_fc[tid];
    __syncthreads();

    if (tid < FOUT * 16) {
        const int f = tid >> 4, sub = tid & 15;
        float vals[8];
        float su = 0.f, sa = 0.f;
        #pragma unroll
        for (int k = 0; k < 8; ++k) {
            float vv = x1l[(sub + 16 * k) * FOUT + f];
            vals[k] = vv;
            su += vv;
            sa += fabsf(vv);
        }
        #pragma unroll
        for (int off = 8; off > 0; off >>= 1) {
            su += __shfl_xor(su, off);
            sa += __shfl_xor(sa, off);
        }
        const float mu = su * (1.0f / (float)BATCH);
        if (sub == 0) out[BATCH * NCLS + f] = sa;          // signal
        float dv = 0.f;
        #pragma unroll
        for (int k = 0; k < 8; ++k) {
            float d = vals[k] - mu;
            dv += d * d;
        }
        #pragma unroll
        for (int off = 8; off > 0; off >>= 1) dv += __shfl_xor(dv, off);
        const float var = dv * (1.0f / (float)BATCH);
        const float rstd = 1.0f / sqrtf(var + 1e-5f);
        const float g = gamma[f], be = beta[f];
        #pragma unroll
        for (int k = 0; k < 8; ++k) {
            float y = g * (vals[k] - mu) * rstd + be;
            x1l[(sub + 16 * k) * FOUT + f] = fmaxf(y, 0.f);
        }
    }
    __syncthreads();

    for (int idx = tid; idx < BATCH * NCLS; idx += 1024) {
        const int bb = idx / NCLS, cc = idx % NCLS;
        float sacc = b_fc[cc];
        #pragma unroll
        for (int f = 0; f < FOUT; ++f)
            sacc += x1l[bb * FOUT + f] * wfc[f * NCLS + cc];
        out[idx] = sacc;
    }

    __syncthreads();
    if (tid == 0)
        __hip_atomic_store(&g_cnt, 0u, __ATOMIC_RELAXED,
                           __HIP_MEMORY_SCOPE_AGENT);   // clean for replay
}

extern "C" void kernel_launch(void* const* d_in, const int* in_sizes, int n_in,
                              void* d_out, int out_size, void* d_ws, size_t ws_size,
                              hipStream_t stream) {
    const float* input  = (const float*)d_in[0];
    const float* W_topo = (const float*)d_in[1];
    const float* b_topo = (const float*)d_in[2];
    const float* gamma  = (const float*)d_in[3];
    const float* beta   = (const float*)d_in[4];
    const float* W_fc   = (const float*)d_in[5];
    const float* b_fc   = (const float*)d_in[6];
    float* out = (float*)d_out;

    k_dtm   <<<dim3(BATCH * NSUB), dim3(128), 0, stream>>>(input);
    k_landbn<<<dim3(BATCH), dim3(1024), 0, stream>>>(W_topo, b_topo,
                                                     gamma, beta, W_fc, b_fc,
                                                     out);
}